// Round 8
// baseline (247.325 us; speedup 1.0000x reference)
//
#include <hip/hip_runtime.h>

#define NN 20000      // nodes
#define FIN 256
#define D1 1024       // H1*C1 = 8*128
#define NH 8
#define C2 128
#define CAP 64        // padded CSR bucket capacity (max degree ~35 incl. self-loop)

typedef unsigned short u16;
typedef unsigned char u8;
typedef __attribute__((ext_vector_type(8))) short bf16x8;
typedef __attribute__((ext_vector_type(4))) float f32x4;
typedef __attribute__((ext_vector_type(2))) float f32x2;

// ---------- bf16 helpers ----------
__device__ __forceinline__ float bf2f(u16 u) {
    return __uint_as_float(((unsigned int)u) << 16);
}
__device__ __forceinline__ u16 f2bf(float f) {
    unsigned int u = __float_as_uint(f);
    u += 0x7FFFu + ((u >> 16) & 1u);   // round-to-nearest-even
    return (u16)(u >> 16);
}
// ---------- fp8 e4m3 (OCP) helpers via HW converts ----------
__device__ __forceinline__ u8 f2fp8(float v) {
    int q = __builtin_amdgcn_cvt_pk_fp8_f32(v, v, 0, false);
    return (u8)(q & 0xFF);
}

// butterfly reductions: every lane ends with the result
__device__ __forceinline__ float bred_max(float v) {
    #pragma unroll
    for (int o = 32; o > 0; o >>= 1) v = fmaxf(v, __shfl_xor(v, o, 64));
    return v;
}
__device__ __forceinline__ float bred_sum(float v) {
    #pragma unroll
    for (int o = 32; o > 0; o >>= 1) v += __shfl_xor(v, o, 64);
    return v;
}

// async global->LDS, 16B per lane (global_load_lds_dwordx4)
typedef const __attribute__((address_space(1))) unsigned int* as1_u32p;
typedef __attribute__((address_space(3))) unsigned int* as3_u32p;
__device__ __forceinline__ void gload_lds16(const void* g, void* l) {
    __builtin_amdgcn_global_load_lds((as1_u32p)g, (as3_u32p)l, 16, 0, 0);
}

// ---------- fused prep: cast x->bf16 | transpose W1/W2 | CSR fill ----------
// cnt is zeroed by hipMemsetAsync BEFORE this kernel, so the fill part can
// run concurrently with the cast/transpose blocks (disjoint data).
// Block ranges: [0,5000) cast, [5000,5256) W1t, [5256,5384) W2t,
// [5384, 5384+ceil((E+NN)/256)) edge fill.
__global__ __launch_bounds__(256) void prep_kernel(const float* __restrict__ x,
                                                   u16* __restrict__ xb,
                                                   const float* __restrict__ W1,
                                                   u16* __restrict__ w1t,
                                                   const float* __restrict__ W2,
                                                   u16* __restrict__ w2t,
                                                   const int* __restrict__ ei,
                                                   int E,
                                                   int* __restrict__ cnt,
                                                   int* __restrict__ csr) {
    __shared__ float tile[32][33];
    const int b = blockIdx.x, tid = threadIdx.x;
    if (b < 5000) {
        int i = (b * 256 + tid) * 4;
        if (i < NN * FIN) {
            float4 v = *(const float4*)(x + i);
            ushort4 o;
            o.x = f2bf(v.x); o.y = f2bf(v.y); o.z = f2bf(v.z); o.w = f2bf(v.w);
            *(ushort4*)(xb + i) = o;
        }
        return;
    }
    if (b < 5384) {
        const float* in; u16* out; int R, C, bx, by;
        if (b < 5256) {
            int q = b - 5000;                 // W1: [FIN x D1] -> [D1 x FIN]
            in = W1; out = w1t; R = FIN; C = D1;
            bx = (q & 31) * 32; by = (q >> 5) * 32;
        } else {
            int q = b - 5256;                 // W2: [D1 x C2] -> [C2 x D1]
            in = W2; out = w2t; R = D1; C = C2;
            bx = (q & 3) * 32; by = (q >> 2) * 32;
        }
        int tx = tid & 31, ty = tid >> 5;     // 32x8
        #pragma unroll
        for (int i = 0; i < 32; i += 8)
            tile[ty + i][tx] = in[(size_t)(by + ty + i) * C + bx + tx];
        __syncthreads();
        #pragma unroll
        for (int i = 0; i < 32; i += 8)
            out[(size_t)(bx + ty + i) * R + by + tx] = f2bf(tile[tx][ty + i]);
        return;
    }
    // ---- padded-bucket CSR fill (self-loops appended) ----
    int j = (b - 5384) * 256 + tid;
    if (j >= E + NN) return;
    int s, d;
    if (j < E) { s = ei[j]; d = ei[E + j]; }
    else { s = j - E; d = j - E; }
    int pos = atomicAdd(&cnt[d], 1);
    if (pos >= CAP) return;   // safety net (never expected)
    csr[d * CAP + pos] = s;
}

// ---------- bf16 MFMA GEMM, 2-phase double-buffered (T3-minimum) ----------
// C[MxN] = A[MxK] * Bt[NxK]^T.  Per K-step: issue next tile's
// global_load_lds into buf^1, then ds_read+MFMA on buf, then ONE
// __syncthreads. Fused per-head attention-dot epilogue.
// OMODE 1: bf16 C out (layer 2); OMODE 2: fp8 e4m3 C out (layer 1).
#define G_STAGE(BUF, K0)                                                   \
    {                                                                      \
        _Pragma("unroll")                                                  \
        for (int i = 0; i < BM / 64; i++) {                                \
            int c = tid + i * 256;                                         \
            int r = c >> 2, ko = (c & 3) * 8;                              \
            int gr = row0 + r; if (gr >= M) gr = M - 1;                    \
            gload_lds16(A + (size_t)gr * K + (K0) + ko,                    \
                        &ldsA[BUF][c * 8]);                                \
        }                                                                  \
        _Pragma("unroll")                                                  \
        for (int i = 0; i < 2; i++) {                                      \
            int c = tid + i * 256;                                         \
            int n = c >> 2, ko = (c & 3) * 8;                              \
            gload_lds16(Bt + (size_t)(col0 + n) * K + (K0) + ko,           \
                        &ldsB[BUF][c * 8]);                                \
        }                                                                  \
    }

template <int BM, int OMODE>
__global__ __launch_bounds__(256) void gemm_mfma(const u16* __restrict__ A,
                                                 const u16* __restrict__ Bt,
                                                 void* __restrict__ C,
                                                 const float* __restrict__ attS,
                                                 const float* __restrict__ attD,
                                                 float* __restrict__ as_out,
                                                 float* __restrict__ ad_out,
                                                 int NHo,
                                                 int M, int N, int K) {
    constexpr int TM = BM / 32;            // 16-tiles per wave along m
    __shared__ u16 ldsA[2][BM * 32];
    __shared__ u16 ldsB[2][128 * 32];
    __shared__ float asb[BM], adb[BM];
    const int tid = threadIdx.x;
    const int lane = tid & 63, w = tid >> 6;
    const int wr = w >> 1, wc = w & 1;
    const int row0 = blockIdx.x * BM, col0 = blockIdx.y * 128;
    const int head = blockIdx.y;
    const int l15 = lane & 15, quad = lane >> 4;

    for (int t = tid; t < BM; t += 256) { asb[t] = 0.f; adb[t] = 0.f; }

    f32x4 acc[TM][4];
    #pragma unroll
    for (int i = 0; i < TM; i++)
        #pragma unroll
        for (int j = 0; j < 4; j++)
            acc[i][j] = (f32x4){0.f, 0.f, 0.f, 0.f};

    G_STAGE(0, 0)
    __syncthreads();
    int cur = 0;
    for (int k0 = 0; k0 < K; k0 += 32) {
        if (k0 + 32 < K) {
            G_STAGE(cur ^ 1, k0 + 32)              // prefetch next K-tile
            __builtin_amdgcn_sched_barrier(0);     // keep issue above compute
        }
        bf16x8 af[TM], bfr[4];
        #pragma unroll
        for (int i = 0; i < TM; i++) {
            int m = wr * (BM / 2) + i * 16 + l15;
            af[i] = *(const bf16x8*)(&ldsA[cur][m * 32 + quad * 8]);
        }
        #pragma unroll
        for (int j = 0; j < 4; j++) {
            int n = wc * 64 + j * 16 + l15;
            bfr[j] = *(const bf16x8*)(&ldsB[cur][n * 32 + quad * 8]);
        }
        #pragma unroll
        for (int i = 0; i < TM; i++)
            #pragma unroll
            for (int j = 0; j < 4; j++)
                acc[i][j] = __builtin_amdgcn_mfma_f32_16x16x32_bf16(af[i], bfr[j], acc[i][j], 0, 0, 0);
        __syncthreads();                           // buf^1 staged + all reads done
        cur ^= 1;
    }
    // ---- C write (fp8 for layer1, bf16 for layer2) ----
    #pragma unroll
    for (int i = 0; i < TM; i++) {
        #pragma unroll
        for (int j = 0; j < 4; j++) {
            #pragma unroll
            for (int r = 0; r < 4; r++) {
                int row = row0 + wr * (BM / 2) + i * 16 + quad * 4 + r;
                int col = col0 + wc * 64 + j * 16 + l15;
                if (row < M) {
                    float v = acc[i][j][r];
                    if (OMODE == 1)
                        ((u16*)C)[(size_t)row * N + col] = f2bf(v);
                    else
                        ((u8*)C)[(size_t)row * N + col] = f2fp8(v);
                }
            }
        }
    }
    // ---- fused per-row attention dots for this head ----
    float attS_r[4], attD_r[4];
    #pragma unroll
    for (int j = 0; j < 4; j++) {
        int col = wc * 64 + j * 16 + l15;
        attS_r[j] = attS[head * 128 + col];
        attD_r[j] = attD[head * 128 + col];
    }
    #pragma unroll
    for (int i = 0; i < TM; i++) {
        #pragma unroll
        for (int r = 0; r < 4; r++) {
            float ps = 0.f, pd = 0.f;
            #pragma unroll
            for (int j = 0; j < 4; j++) {
                float v = acc[i][j][r];
                ps = fmaf(v, attS_r[j], ps);
                pd = fmaf(v, attD_r[j], pd);
            }
            #pragma unroll
            for (int o = 1; o < 16; o <<= 1) {
                ps += __shfl_xor(ps, o, 64);
                pd += __shfl_xor(pd, o, 64);
            }
            if (l15 == 0) {
                int row = wr * (BM / 2) + i * 16 + quad * 4 + r;
                atomicAdd(&asb[row], ps);
                atomicAdd(&adb[row], pd);
            }
        }
    }
    __syncthreads();
    for (int t = tid; t < BM; t += 256) {
        int row = row0 + t;
        if (row < M) {
            as_out[(size_t)row * NHo + head] = asb[t];
            ad_out[(size_t)row * NHo + head] = adb[t];
        }
    }
}

// ---------- layer-1 softmax-aggregate + ELU (WIDE, R4 structure) ----------
// ONE WAVE per dst, 16 ch/lane covering all 1024 ch; GROUP=8 depth-2
// ping-pong; inline per-edge as1 weight load (L2-resident 640KB table).
// Fabric-bound at ~3.4-3.9 TB/s (measured R4/R7); latency and VALU trims
// don't move it. Launched as FOUR quarter-dispatches (d0 offset) this
// round: same total work, sinks agg1's rows to ~15us in the profile so
// the top-5 table surfaces the largest OTHER kernel (diagnostic - the
// remaining ~170us is otherwise invisible).
#define A1_FETCH8(E0, Q, P)                                                   \
    {                                                                         \
        _Pragma("unroll")                                                     \
        for (int u = 0; u < 8; u++) {                                         \
            int e = (E0) + u;             /* e <= 63 < CAP always */          \
            int s = __builtin_amdgcn_readlane(idx, e);                        \
            s = s < 0 ? 0 : (s > NN - 1 ? NN - 1 : s);   /* SALU clamp */     \
            Q[u] = *(const uint4*)(h1q + (size_t)s * D1 + c0);                \
            P[u] = as1[s * NH + h];       /* L2-hit 4B; masked at PROC */     \
        }                                                                     \
        __builtin_amdgcn_sched_barrier(0);                                    \
    }
#define A1_PROC8(E0, Q, P)                                                    \
    {                                                                         \
        _Pragma("unroll")                                                     \
        for (int u = 0; u < 8; u++) {                                         \
            float ev = (P)[u] + adv;                                          \
            ev = ev > 0.f ? ev : 0.2f * ev;           /* LeakyReLU(0.2) */    \
            float pp = ((E0) + u < deg) ? __expf(ev) : 0.f;                   \
            den += pp;                                                        \
            f32x2 pv2 = {pp, pp};                                             \
            acc[0] += pv2 * __builtin_amdgcn_cvt_pk_f32_fp8((Q)[u].x, false); \
            acc[1] += pv2 * __builtin_amdgcn_cvt_pk_f32_fp8((Q)[u].x, true);  \
            acc[2] += pv2 * __builtin_amdgcn_cvt_pk_f32_fp8((Q)[u].y, false); \
            acc[3] += pv2 * __builtin_amdgcn_cvt_pk_f32_fp8((Q)[u].y, true);  \
            acc[4] += pv2 * __builtin_amdgcn_cvt_pk_f32_fp8((Q)[u].z, false); \
            acc[5] += pv2 * __builtin_amdgcn_cvt_pk_f32_fp8((Q)[u].z, true);  \
            acc[6] += pv2 * __builtin_amdgcn_cvt_pk_f32_fp8((Q)[u].w, false); \
            acc[7] += pv2 * __builtin_amdgcn_cvt_pk_f32_fp8((Q)[u].w, true);  \
        }                                                                     \
    }

__global__ __launch_bounds__(256) void agg1_kernel(const u8* __restrict__ h1q,
                                                   const float* __restrict__ as1,
                                                   const float* __restrict__ ad1,
                                                   const int* __restrict__ cnt,
                                                   const int* __restrict__ csr,
                                                   const float* __restrict__ bias1,
                                                   u16* __restrict__ x2,
                                                   int d0) {
    const int tid = threadIdx.x;
    const int lane = tid & 63;
    const int dst = d0 + (blockIdx.x << 2) + (tid >> 6);
    const int c0 = lane * 16;               // 16 channels per lane
    const int h = lane >> 3;                // head (all 16 lane-channels same head)
    const int base = dst * CAP;

    int idx = csr[base + lane];                     // unclamped: || with cnt load
    const int deg = __builtin_amdgcn_readfirstlane(max(1, min(cnt[dst], CAP)));
    const float adv = ad1[dst * NH + h];            // per-head dst term

    f32x2 acc[8];
    #pragma unroll
    for (int k = 0; k < 8; k++) acc[k] = (f32x2){0.f, 0.f};
    float den = 0.f;

    const int nit = (deg + 7) >> 3;                 // groups of 8
    uint4 qa[8], qb[8];
    float pa[8], pb[8];
    A1_FETCH8(0, qa, pa)
    int g = 0;
    for (; g + 2 < nit; g += 2) {                   // ping-pong
        A1_FETCH8((g + 1) * 8, qb, pb)
        A1_PROC8(g * 8, qa, pa)
        A1_FETCH8((g + 2) * 8, qa, pa)
        A1_PROC8((g + 1) * 8, qb, pb)
    }
    if (g + 1 < nit) {
        A1_FETCH8((g + 1) * 8, qb, pb)
        A1_PROC8(g * 8, qa, pa)
        A1_PROC8((g + 1) * 8, qb, pb)
    } else {
        A1_PROC8(g * 8, qa, pa)
    }

    float inv = 1.f / (den + 1e-16f);
    u16 ov[16];
    #pragma unroll
    for (int k = 0; k < 8; k++) {
        float a0 = acc[k][0] * inv + bias1[c0 + 2 * k];
        float a1 = acc[k][1] * inv + bias1[c0 + 2 * k + 1];
        a0 = a0 > 0.f ? a0 : (__expf(a0) - 1.f);   // ELU (abs err ~1e-7, tol 0.03)
        a1 = a1 > 0.f ? a1 : (__expf(a1) - 1.f);
        ov[2 * k] = f2bf(a0);
        ov[2 * k + 1] = f2bf(a1);
    }
    *(uint4*)(x2 + (size_t)dst * D1 + c0) = *(const uint4*)ov;
    *(uint4*)(x2 + (size_t)dst * D1 + c0 + 8) = *(const uint4*)(ov + 8);
}

// ---------- layer-2 softmax-aggregate + log_softmax, lean PROC (R6) ----------
// ONE WAVE per dst; hoisted den / pre-masked pl / scalar-fmaf.
#define A2_FETCH8(E0, Q)                                                      \
    {                                                                         \
        _Pragma("unroll")                                                     \
        for (int u = 0; u < 8; u++) {                                         \
            int s = __builtin_amdgcn_readlane(idx, (E0) + u);                 \
            s = s < 0 ? 0 : (s > NN - 1 ? NN - 1 : s);                        \
            Q[u] = *(const unsigned int*)(h2 + (size_t)s * C2 + lane2);       \
        }                                                                     \
        __builtin_amdgcn_sched_barrier(0);                                    \
    }
#define A2_PROC8(E0, Q)                                                       \
    {                                                                         \
        _Pragma("unroll")                                                     \
        for (int u = 0; u < 8; u++) {                                         \
            float pp = __uint_as_float(__builtin_amdgcn_readlane(             \
                __float_as_uint(pl), (E0) + u));                              \
            float f0 = __uint_as_float((Q)[u] << 16);                         \
            float f1 = __uint_as_float((Q)[u] & 0xFFFF0000u);                 \
            a0 = fmaf(pp, f0, a0);                                            \
            a1 = fmaf(pp, f1, a1);                                            \
        }                                                                     \
    }

__global__ __launch_bounds__(256) void agg2_kernel(const u16* __restrict__ h2,
                                                   const float* __restrict__ as2,
                                                   const float* __restrict__ ad2,
                                                   const int* __restrict__ cnt,
                                                   const int* __restrict__ csr,
                                                   const float* __restrict__ bias2,
                                                   float* __restrict__ out) {
    const int tid = threadIdx.x;
    const int lane = tid & 63;
    const int dst = (blockIdx.x << 2) + __builtin_amdgcn_readfirstlane(tid >> 6);
    const int base = dst * CAP;
    const int lane2 = lane * 2;

    int idx = csr[base + lane];                 // coalesced; || with cnt
    const int deg = max(1, min(cnt[dst], CAP)); // scalar
    const float adv = ad2[dst];
    int idxc = idx < 0 ? 0 : (idx > NN - 1 ? NN - 1 : idx);
    float ev = as2[idxc] + adv;                 // random 4B within 80 KB (L2)
    ev = ev > 0.f ? ev : 0.2f * ev;
    float pl = (lane < deg) ? __expf(ev) : 0.f; // masked ONCE
    float den = bred_sum(pl);                   // hoisted

    float a0 = 0.f, a1 = 0.f;

    const int nit = (deg + 7) >> 3;
    unsigned int qa[8], qb[8];
    A2_FETCH8(0, qa)
    int g = 0;
    for (; g + 2 < nit; g += 2) {
        A2_FETCH8((g + 1) * 8, qb)
        A2_PROC8(g * 8, qa)
        A2_FETCH8((g + 2) * 8, qa)
        A2_PROC8((g + 1) * 8, qb)
    }
    if (g + 1 < nit) {
        A2_FETCH8((g + 1) * 8, qb)
        A2_PROC8(g * 8, qa)
        A2_PROC8((g + 1) * 8, qb)
    } else {
        A2_PROC8(g * 8, qa)
    }

    float inv = 1.f / (den + 1e-16f);
    float l0 = a0 * inv + bias2[lane2];
    float l1 = a1 * inv + bias2[lane2 + 1];
    // log_softmax over the wave's 128 channels
    float m = bred_max(fmaxf(l0, l1));
    float ex = bred_sum(__expf(l0 - m) + __expf(l1 - m));
    float lse = m + __logf(ex);
    float2 ov = {l0 - lse, l1 - lse};
    *(float2*)(out + (size_t)dst * C2 + lane2) = ov;
}

extern "C" void kernel_launch(void* const* d_in, const int* in_sizes, int n_in,
                              void* d_out, int out_size, void* d_ws, size_t ws_size,
                              hipStream_t stream) {
    const float* x        = (const float*)d_in[0];
    const int*   ei       = (const int*)d_in[1];
    const float* W1       = (const float*)d_in[2];
    const float* att_src1 = (const float*)d_in[3];
    const float* att_dst1 = (const float*)d_in[4];
    const float* bias1    = (const float*)d_in[5];
    const float* W2       = (const float*)d_in[6];
    const float* att_src2 = (const float*)d_in[7];
    const float* att_dst2 = (const float*)d_in[8];
    const float* bias2    = (const float*)d_in[9];
    float* out = (float*)d_out;
    const int E = in_sizes[1] / 2;

    char* ws = (char*)d_ws;
    size_t off = 0;
    auto alloc = [&](size_t b) {
        void* p = ws + off;
        off += (b + 255) & ~(size_t)255;
        return p;
    };
    u8*  h1q  = (u8*)alloc((size_t)NN * D1);
    u16* x2   = (u16*)alloc((size_t)NN * D1 * 2);
    u16* h2   = (u16*)alloc((size_t)NN * C2 * 2);
    u16* xb   = (u16*)alloc((size_t)NN * FIN * 2);
    u16* w1t  = (u16*)alloc((size_t)D1 * FIN * 2);
    u16* w2t  = (u16*)alloc((size_t)C2 * D1 * 2);
    float* as1 = (float*)alloc((size_t)NN * NH * 4);
    float* ad1 = (float*)alloc((size_t)NN * NH * 4);
    float* as2 = (float*)alloc((size_t)NN * 4);
    float* ad2 = (float*)alloc((size_t)NN * 4);
    int* cnt  = (int*)alloc((size_t)NN * 4);
    int* csr  = (int*)alloc((size_t)NN * CAP * 4);

    // zero cnt up front; fused prep then casts x, transposes W1/W2 AND
    // fills the CSR buckets (fill overlaps the BW-heavy cast blocks)
    hipMemsetAsync(cnt, 0, (size_t)NN * 4, stream);
    const int FILL_BLOCKS = (E + NN + 255) / 256;
    prep_kernel<<<5384 + FILL_BLOCKS, 256, 0, stream>>>(x, xb, W1, w1t, W2, w2t,
                                                        ei, E, cnt, csr);

    // layer 1 GEMM: h1q fp8 + fused per-head as1/ad1
    gemm_mfma<128, 2><<<dim3((NN + 127) / 128, D1 / 128), 256, 0, stream>>>(
        xb, w1t, h1q, att_src1, att_dst1, as1, ad1, NH, NN, D1, FIN);
    // agg1 as 4 quarter-dispatches (5000 dsts each): same total work;
    // sinks agg1 rows in the profile so other kernels surface (diagnostic)
    for (int q = 0; q < 4; q++)
        agg1_kernel<<<1250, 256, 0, stream>>>(h1q, as1, ad1, cnt, csr,
                                              bias1, x2, q * 5000);
    // layer 2 GEMM: h2 bf16 + fused as2/ad2
    gemm_mfma<64, 1><<<dim3((NN + 63) / 64, C2 / 128), 256, 0, stream>>>(
        x2, w2t, h2, att_src2, att_dst2, as2, ad2, 1, NN, C2, D1);
    agg2_kernel<<<(NN + 3) / 4, 256, 0, stream>>>(h2, as2, ad2, cnt, csr, bias2, out);
}

// Round 9
// 234.503 us; speedup vs baseline: 1.0547x; 1.0547x over previous
//
#include <hip/hip_runtime.h>

#define NN 20000      // nodes
#define FIN 256
#define D1 1024       // H1*C1 = 8*128
#define NH 8
#define C2 128
#define CAP 64        // padded CSR bucket capacity (max degree ~35 incl. self-loop)

typedef unsigned short u16;
typedef unsigned char u8;
typedef __attribute__((ext_vector_type(8))) short bf16x8;
typedef __attribute__((ext_vector_type(4))) float f32x4;
typedef __attribute__((ext_vector_type(2))) float f32x2;

// ---------- bf16 helpers ----------
__device__ __forceinline__ float bf2f(u16 u) {
    return __uint_as_float(((unsigned int)u) << 16);
}
__device__ __forceinline__ u16 f2bf(float f) {
    unsigned int u = __float_as_uint(f);
    u += 0x7FFFu + ((u >> 16) & 1u);   // round-to-nearest-even
    return (u16)(u >> 16);
}
// ---------- fp8 e4m3 (OCP) helpers via HW converts ----------
__device__ __forceinline__ u8 f2fp8(float v) {
    int q = __builtin_amdgcn_cvt_pk_fp8_f32(v, v, 0, false);
    return (u8)(q & 0xFF);
}

// butterfly reductions: every lane ends with the result
__device__ __forceinline__ float bred_max(float v) {
    #pragma unroll
    for (int o = 32; o > 0; o >>= 1) v = fmaxf(v, __shfl_xor(v, o, 64));
    return v;
}
__device__ __forceinline__ float bred_sum(float v) {
    #pragma unroll
    for (int o = 32; o > 0; o >>= 1) v += __shfl_xor(v, o, 64);
    return v;
}

// async global->LDS, 16B per lane (global_load_lds_dwordx4)
typedef const __attribute__((address_space(1))) unsigned int* as1_u32p;
typedef __attribute__((address_space(3))) unsigned int* as3_u32p;
__device__ __forceinline__ void gload_lds16(const void* g, void* l) {
    __builtin_amdgcn_global_load_lds((as1_u32p)g, (as3_u32p)l, 16, 0, 0);
}

// ---------- fused prep: cast x->bf16 | transpose W1/W2 | CSR fill ----------
// cnt is zeroed by hipMemsetAsync BEFORE this kernel, so the fill part can
// run concurrently with the cast/transpose blocks (disjoint data).
// Block ranges: [0,5000) cast, [5000,5256) W1t, [5256,5384) W2t,
// [5384, 5384+ceil((E+NN)/256)) edge fill.
__global__ __launch_bounds__(256) void prep_kernel(const float* __restrict__ x,
                                                   u16* __restrict__ xb,
                                                   const float* __restrict__ W1,
                                                   u16* __restrict__ w1t,
                                                   const float* __restrict__ W2,
                                                   u16* __restrict__ w2t,
                                                   const int* __restrict__ ei,
                                                   int E,
                                                   int* __restrict__ cnt,
                                                   int* __restrict__ csr) {
    __shared__ float tile[32][33];
    const int b = blockIdx.x, tid = threadIdx.x;
    if (b < 5000) {
        int i = (b * 256 + tid) * 4;
        if (i < NN * FIN) {
            float4 v = *(const float4*)(x + i);
            ushort4 o;
            o.x = f2bf(v.x); o.y = f2bf(v.y); o.z = f2bf(v.z); o.w = f2bf(v.w);
            *(ushort4*)(xb + i) = o;
        }
        return;
    }
    if (b < 5384) {
        const float* in; u16* out; int R, C, bx, by;
        if (b < 5256) {
            int q = b - 5000;                 // W1: [FIN x D1] -> [D1 x FIN]
            in = W1; out = w1t; R = FIN; C = D1;
            bx = (q & 31) * 32; by = (q >> 5) * 32;
        } else {
            int q = b - 5256;                 // W2: [D1 x C2] -> [C2 x D1]
            in = W2; out = w2t; R = D1; C = C2;
            bx = (q & 3) * 32; by = (q >> 2) * 32;
        }
        int tx = tid & 31, ty = tid >> 5;     // 32x8
        #pragma unroll
        for (int i = 0; i < 32; i += 8)
            tile[ty + i][tx] = in[(size_t)(by + ty + i) * C + bx + tx];
        __syncthreads();
        #pragma unroll
        for (int i = 0; i < 32; i += 8)
            out[(size_t)(bx + ty + i) * R + by + tx] = f2bf(tile[tx][ty + i]);
        return;
    }
    // ---- padded-bucket CSR fill (self-loops appended) ----
    int j = (b - 5384) * 256 + tid;
    if (j >= E + NN) return;
    int s, d;
    if (j < E) { s = ei[j]; d = ei[E + j]; }
    else { s = j - E; d = j - E; }
    int pos = atomicAdd(&cnt[d], 1);
    if (pos >= CAP) return;   // safety net (never expected)
    csr[d * CAP + pos] = s;
}

// ---------- bf16 MFMA GEMM, 2-phase double-buffered, generic BK ----------
// C[MxN] = A[MxK] * Bt[NxK]^T.  Per K-step: issue next tile's
// global_load_lds into buf^1, then ds_read+MFMA on buf, then ONE
// __syncthreads. Fused per-head attention-dot epilogue.
// OMODE 1: bf16 C out (layer 2); OMODE 2: fp8 e4m3 C out (layer 1).
// gemm2's R7 config (BM=64,BK=32) was structurally latency-bound:
// 313 blocks = 1.2/CU and 32 serial barriered K-steps. Now BM=32,BK=64:
// 625 blocks (2.4/CU, ~10 waves/CU) and 16 serial steps.
#define G_STAGE(BUF, K0)                                                   \
    {                                                                      \
        constexpr int CPR = BK / 8;   /* 16B chunks per row */             \
        _Pragma("unroll")                                                  \
        for (int i = 0; i < BM * BK / 8 / 256; i++) {                      \
            int c = tid + i * 256;                                         \
            int r = c / CPR, ko = (c % CPR) * 8;                           \
            int gr = row0 + r; if (gr >= M) gr = M - 1;                    \
            gload_lds16(A + (size_t)gr * K + (K0) + ko,                    \
                        &ldsA[BUF][c * 8]);                                \
        }                                                                  \
        _Pragma("unroll")                                                  \
        for (int i = 0; i < 128 * BK / 8 / 256; i++) {                     \
            int c = tid + i * 256;                                         \
            int n = c / CPR, ko = (c % CPR) * 8;                           \
            gload_lds16(Bt + (size_t)(col0 + n) * K + (K0) + ko,           \
                        &ldsB[BUF][c * 8]);                                \
        }                                                                  \
    }

template <int BM, int BK, int OMODE>
__global__ __launch_bounds__(256) void gemm_mfma(const u16* __restrict__ A,
                                                 const u16* __restrict__ Bt,
                                                 void* __restrict__ C,
                                                 const float* __restrict__ attS,
                                                 const float* __restrict__ attD,
                                                 float* __restrict__ as_out,
                                                 float* __restrict__ ad_out,
                                                 int NHo,
                                                 int M, int N, int K) {
    constexpr int TM = BM / 32;            // 16-tiles per wave along m
    constexpr int KK = BK / 32;            // MFMA k-substeps per K-step
    __shared__ u16 ldsA[2][BM * BK];
    __shared__ u16 ldsB[2][128 * BK];
    __shared__ float asb[BM], adb[BM];
    const int tid = threadIdx.x;
    const int lane = tid & 63, w = tid >> 6;
    const int wr = w >> 1, wc = w & 1;
    const int row0 = blockIdx.x * BM, col0 = blockIdx.y * 128;
    const int head = blockIdx.y;
    const int l15 = lane & 15, quad = lane >> 4;

    for (int t = tid; t < BM; t += 256) { asb[t] = 0.f; adb[t] = 0.f; }

    f32x4 acc[TM][4];
    #pragma unroll
    for (int i = 0; i < TM; i++)
        #pragma unroll
        for (int j = 0; j < 4; j++)
            acc[i][j] = (f32x4){0.f, 0.f, 0.f, 0.f};

    G_STAGE(0, 0)
    __syncthreads();
    int cur = 0;
    for (int k0 = 0; k0 < K; k0 += BK) {
        if (k0 + BK < K) {
            G_STAGE(cur ^ 1, k0 + BK)              // prefetch next K-tile
            __builtin_amdgcn_sched_barrier(0);     // keep issue above compute
        }
        bf16x8 af[TM][KK], bfr[KK][4];
        #pragma unroll
        for (int i = 0; i < TM; i++) {
            int m = wr * (BM / 2) + i * 16 + l15;
            #pragma unroll
            for (int kk = 0; kk < KK; kk++)
                af[i][kk] = *(const bf16x8*)(&ldsA[cur][m * BK + kk * 32 + quad * 8]);
        }
        #pragma unroll
        for (int j = 0; j < 4; j++) {
            int n = wc * 64 + j * 16 + l15;
            #pragma unroll
            for (int kk = 0; kk < KK; kk++)
                bfr[kk][j] = *(const bf16x8*)(&ldsB[cur][n * BK + kk * 32 + quad * 8]);
        }
        #pragma unroll
        for (int i = 0; i < TM; i++)
            #pragma unroll
            for (int kk = 0; kk < KK; kk++)
                #pragma unroll
                for (int j = 0; j < 4; j++)
                    acc[i][j] = __builtin_amdgcn_mfma_f32_16x16x32_bf16(af[i][kk], bfr[kk][j], acc[i][j], 0, 0, 0);
        __syncthreads();                           // buf^1 staged + all reads done
        cur ^= 1;
    }
    // ---- C write (fp8 for layer1, bf16 for layer2) ----
    #pragma unroll
    for (int i = 0; i < TM; i++) {
        #pragma unroll
        for (int j = 0; j < 4; j++) {
            #pragma unroll
            for (int r = 0; r < 4; r++) {
                int row = row0 + wr * (BM / 2) + i * 16 + quad * 4 + r;
                int col = col0 + wc * 64 + j * 16 + l15;
                if (row < M) {
                    float v = acc[i][j][r];
                    if (OMODE == 1)
                        ((u16*)C)[(size_t)row * N + col] = f2bf(v);
                    else
                        ((u8*)C)[(size_t)row * N + col] = f2fp8(v);
                }
            }
        }
    }
    // ---- fused per-row attention dots for this head ----
    float attS_r[4], attD_r[4];
    #pragma unroll
    for (int j = 0; j < 4; j++) {
        int col = wc * 64 + j * 16 + l15;
        attS_r[j] = attS[head * 128 + col];
        attD_r[j] = attD[head * 128 + col];
    }
    #pragma unroll
    for (int i = 0; i < TM; i++) {
        #pragma unroll
        for (int r = 0; r < 4; r++) {
            float ps = 0.f, pd = 0.f;
            #pragma unroll
            for (int j = 0; j < 4; j++) {
                float v = acc[i][j][r];
                ps = fmaf(v, attS_r[j], ps);
                pd = fmaf(v, attD_r[j], pd);
            }
            #pragma unroll
            for (int o = 1; o < 16; o <<= 1) {
                ps += __shfl_xor(ps, o, 64);
                pd += __shfl_xor(pd, o, 64);
            }
            if (l15 == 0) {
                int row = wr * (BM / 2) + i * 16 + quad * 4 + r;
                atomicAdd(&asb[row], ps);
                atomicAdd(&adb[row], pd);
            }
        }
    }
    __syncthreads();
    for (int t = tid; t < BM; t += 256) {
        int row = row0 + t;
        if (row < M) {
            as_out[(size_t)row * NHo + head] = asb[t];
            ad_out[(size_t)row * NHo + head] = adb[t];
        }
    }
}

// ---------- layer-1 softmax-aggregate + ELU (WIDE, R4/R7 structure) ----------
// ONE WAVE per dst, 16 ch/lane covering all 1024 ch; GROUP=8 depth-2
// ping-pong; inline per-edge as1 weight load (L2-resident 640KB table).
// Fabric-bound at ~3.4-3.9 TB/s (measured R4/R7); latency and VALU trims
// don't move it (R3/R5/R6). Single dispatch (R8's 4-way split cost ~17us
// in dispatch tails - reverted).
#define A1_FETCH8(E0, Q, P)                                                   \
    {                                                                         \
        _Pragma("unroll")                                                     \
        for (int u = 0; u < 8; u++) {                                         \
            int e = (E0) + u;             /* e <= 63 < CAP always */          \
            int s = __builtin_amdgcn_readlane(idx, e);                        \
            s = s < 0 ? 0 : (s > NN - 1 ? NN - 1 : s);   /* SALU clamp */     \
            Q[u] = *(const uint4*)(h1q + (size_t)s * D1 + c0);                \
            P[u] = as1[s * NH + h];       /* L2-hit 4B; masked at PROC */     \
        }                                                                     \
        __builtin_amdgcn_sched_barrier(0);                                    \
    }
#define A1_PROC8(E0, Q, P)                                                    \
    {                                                                         \
        _Pragma("unroll")                                                     \
        for (int u = 0; u < 8; u++) {                                         \
            float ev = (P)[u] + adv;                                          \
            ev = ev > 0.f ? ev : 0.2f * ev;           /* LeakyReLU(0.2) */    \
            float pp = ((E0) + u < deg) ? __expf(ev) : 0.f;                   \
            den += pp;                                                        \
            f32x2 pv2 = {pp, pp};                                             \
            acc[0] += pv2 * __builtin_amdgcn_cvt_pk_f32_fp8((Q)[u].x, false); \
            acc[1] += pv2 * __builtin_amdgcn_cvt_pk_f32_fp8((Q)[u].x, true);  \
            acc[2] += pv2 * __builtin_amdgcn_cvt_pk_f32_fp8((Q)[u].y, false); \
            acc[3] += pv2 * __builtin_amdgcn_cvt_pk_f32_fp8((Q)[u].y, true);  \
            acc[4] += pv2 * __builtin_amdgcn_cvt_pk_f32_fp8((Q)[u].z, false); \
            acc[5] += pv2 * __builtin_amdgcn_cvt_pk_f32_fp8((Q)[u].z, true);  \
            acc[6] += pv2 * __builtin_amdgcn_cvt_pk_f32_fp8((Q)[u].w, false); \
            acc[7] += pv2 * __builtin_amdgcn_cvt_pk_f32_fp8((Q)[u].w, true);  \
        }                                                                     \
    }

__global__ __launch_bounds__(256) void agg1_kernel(const u8* __restrict__ h1q,
                                                   const float* __restrict__ as1,
                                                   const float* __restrict__ ad1,
                                                   const int* __restrict__ cnt,
                                                   const int* __restrict__ csr,
                                                   const float* __restrict__ bias1,
                                                   u16* __restrict__ x2) {
    const int tid = threadIdx.x;
    const int lane = tid & 63;
    const int dst = (blockIdx.x << 2) + (tid >> 6);
    const int c0 = lane * 16;               // 16 channels per lane
    const int h = lane >> 3;                // head (all 16 lane-channels same head)
    const int base = dst * CAP;

    int idx = csr[base + lane];                     // unclamped: || with cnt load
    const int deg = __builtin_amdgcn_readfirstlane(max(1, min(cnt[dst], CAP)));
    const float adv = ad1[dst * NH + h];            // per-head dst term

    f32x2 acc[8];
    #pragma unroll
    for (int k = 0; k < 8; k++) acc[k] = (f32x2){0.f, 0.f};
    float den = 0.f;

    const int nit = (deg + 7) >> 3;                 // groups of 8
    uint4 qa[8], qb[8];
    float pa[8], pb[8];
    A1_FETCH8(0, qa, pa)
    int g = 0;
    for (; g + 2 < nit; g += 2) {                   // ping-pong
        A1_FETCH8((g + 1) * 8, qb, pb)
        A1_PROC8(g * 8, qa, pa)
        A1_FETCH8((g + 2) * 8, qa, pa)
        A1_PROC8((g + 1) * 8, qb, pb)
    }
    if (g + 1 < nit) {
        A1_FETCH8((g + 1) * 8, qb, pb)
        A1_PROC8(g * 8, qa, pa)
        A1_PROC8((g + 1) * 8, qb, pb)
    } else {
        A1_PROC8(g * 8, qa, pa)
    }

    float inv = 1.f / (den + 1e-16f);
    u16 ov[16];
    #pragma unroll
    for (int k = 0; k < 8; k++) {
        float a0 = acc[k][0] * inv + bias1[c0 + 2 * k];
        float a1 = acc[k][1] * inv + bias1[c0 + 2 * k + 1];
        a0 = a0 > 0.f ? a0 : (__expf(a0) - 1.f);   // ELU (abs err ~1e-7, tol 0.03)
        a1 = a1 > 0.f ? a1 : (__expf(a1) - 1.f);
        ov[2 * k] = f2bf(a0);
        ov[2 * k + 1] = f2bf(a1);
    }
    *(uint4*)(x2 + (size_t)dst * D1 + c0) = *(const uint4*)ov;
    *(uint4*)(x2 + (size_t)dst * D1 + c0 + 8) = *(const uint4*)(ov + 8);
}

// ---------- layer-2 softmax-aggregate + log_softmax, lean PROC (R6) ----------
// ONE WAVE per dst; hoisted den / pre-masked pl / scalar-fmaf.
#define A2_FETCH8(E0, Q)                                                      \
    {                                                                         \
        _Pragma("unroll")                                                     \
        for (int u = 0; u < 8; u++) {                                         \
            int s = __builtin_amdgcn_readlane(idx, (E0) + u);                 \
            s = s < 0 ? 0 : (s > NN - 1 ? NN - 1 : s);                        \
            Q[u] = *(const unsigned int*)(h2 + (size_t)s * C2 + lane2);       \
        }                                                                     \
        __builtin_amdgcn_sched_barrier(0);                                    \
    }
#define A2_PROC8(E0, Q)                                                       \
    {                                                                         \
        _Pragma("unroll")                                                     \
        for (int u = 0; u < 8; u++) {                                         \
            float pp = __uint_as_float(__builtin_amdgcn_readlane(             \
                __float_as_uint(pl), (E0) + u));                              \
            float f0 = __uint_as_float((Q)[u] << 16);                         \
            float f1 = __uint_as_float((Q)[u] & 0xFFFF0000u);                 \
            a0 = fmaf(pp, f0, a0);                                            \
            a1 = fmaf(pp, f1, a1);                                            \
        }                                                                     \
    }

__global__ __launch_bounds__(256) void agg2_kernel(const u16* __restrict__ h2,
                                                   const float* __restrict__ as2,
                                                   const float* __restrict__ ad2,
                                                   const int* __restrict__ cnt,
                                                   const int* __restrict__ csr,
                                                   const float* __restrict__ bias2,
                                                   float* __restrict__ out) {
    const int tid = threadIdx.x;
    const int lane = tid & 63;
    const int dst = (blockIdx.x << 2) + __builtin_amdgcn_readfirstlane(tid >> 6);
    const int base = dst * CAP;
    const int lane2 = lane * 2;

    int idx = csr[base + lane];                 // coalesced; || with cnt
    const int deg = max(1, min(cnt[dst], CAP)); // scalar
    const float adv = ad2[dst];
    int idxc = idx < 0 ? 0 : (idx > NN - 1 ? NN - 1 : idx);
    float ev = as2[idxc] + adv;                 // random 4B within 80 KB (L2)
    ev = ev > 0.f ? ev : 0.2f * ev;
    float pl = (lane < deg) ? __expf(ev) : 0.f; // masked ONCE
    float den = bred_sum(pl);                   // hoisted

    float a0 = 0.f, a1 = 0.f;

    const int nit = (deg + 7) >> 3;
    unsigned int qa[8], qb[8];
    A2_FETCH8(0, qa)
    int g = 0;
    for (; g + 2 < nit; g += 2) {
        A2_FETCH8((g + 1) * 8, qb)
        A2_PROC8(g * 8, qa)
        A2_FETCH8((g + 2) * 8, qa)
        A2_PROC8((g + 1) * 8, qb)
    }
    if (g + 1 < nit) {
        A2_FETCH8((g + 1) * 8, qb)
        A2_PROC8(g * 8, qa)
        A2_PROC8((g + 1) * 8, qb)
    } else {
        A2_PROC8(g * 8, qa)
    }

    float inv = 1.f / (den + 1e-16f);
    float l0 = a0 * inv + bias2[lane2];
    float l1 = a1 * inv + bias2[lane2 + 1];
    // log_softmax over the wave's 128 channels
    float m = bred_max(fmaxf(l0, l1));
    float ex = bred_sum(__expf(l0 - m) + __expf(l1 - m));
    float lse = m + __logf(ex);
    float2 ov = {l0 - lse, l1 - lse};
    *(float2*)(out + (size_t)dst * C2 + lane2) = ov;
}

extern "C" void kernel_launch(void* const* d_in, const int* in_sizes, int n_in,
                              void* d_out, int out_size, void* d_ws, size_t ws_size,
                              hipStream_t stream) {
    const float* x        = (const float*)d_in[0];
    const int*   ei       = (const int*)d_in[1];
    const float* W1       = (const float*)d_in[2];
    const float* att_src1 = (const float*)d_in[3];
    const float* att_dst1 = (const float*)d_in[4];
    const float* bias1    = (const float*)d_in[5];
    const float* W2       = (const float*)d_in[6];
    const float* att_src2 = (const float*)d_in[7];
    const float* att_dst2 = (const float*)d_in[8];
    const float* bias2    = (const float*)d_in[9];
    float* out = (float*)d_out;
    const int E = in_sizes[1] / 2;

    char* ws = (char*)d_ws;
    size_t off = 0;
    auto alloc = [&](size_t b) {
        void* p = ws + off;
        off += (b + 255) & ~(size_t)255;
        return p;
    };
    u8*  h1q  = (u8*)alloc((size_t)NN * D1);
    u16* x2   = (u16*)alloc((size_t)NN * D1 * 2);
    u16* h2   = (u16*)alloc((size_t)NN * C2 * 2);
    u16* xb   = (u16*)alloc((size_t)NN * FIN * 2);
    u16* w1t  = (u16*)alloc((size_t)D1 * FIN * 2);
    u16* w2t  = (u16*)alloc((size_t)C2 * D1 * 2);
    float* as1 = (float*)alloc((size_t)NN * NH * 4);
    float* ad1 = (float*)alloc((size_t)NN * NH * 4);
    float* as2 = (float*)alloc((size_t)NN * 4);
    float* ad2 = (float*)alloc((size_t)NN * 4);
    int* cnt  = (int*)alloc((size_t)NN * 4);
    int* csr  = (int*)alloc((size_t)NN * CAP * 4);

    // zero cnt up front; fused prep then casts x, transposes W1/W2 AND
    // fills the CSR buckets (fill overlaps the BW-heavy cast blocks)
    hipMemsetAsync(cnt, 0, (size_t)NN * 4, stream);
    const int FILL_BLOCKS = (E + NN + 255) / 256;
    prep_kernel<<<5384 + FILL_BLOCKS, 256, 0, stream>>>(x, xb, W1, w1t, W2, w2t,
                                                        ei, E, cnt, csr);

    // layer 1 GEMM: h1q fp8 + fused per-head as1/ad1
    gemm_mfma<128, 32, 2><<<dim3((NN + 127) / 128, D1 / 128), 256, 0, stream>>>(
        xb, w1t, h1q, att_src1, att_dst1, as1, ad1, NH, NN, D1, FIN);
    // 1 wave per dst: 20000 waves = 5000 blocks (single dispatch; R8's
    // 4-way split cost ~17us in tails)
    agg1_kernel<<<(NN + 3) / 4, 256, 0, stream>>>(h1q, as1, ad1, cnt, csr,
                                                  bias1, x2);
    // layer 2 GEMM: h2 bf16 + fused as2/ad2. BM=32/BK=64: 625 blocks
    // (2.4/CU) and 16 serial K-steps vs R7's 313 blocks / 32 steps.
    gemm_mfma<32, 64, 1><<<dim3((NN + 31) / 32, C2 / 128), 256, 0, stream>>>(
        x2, w2t, h2, att_src2, att_dst2, as2, ad2, 1, NN, C2, D1);
    agg2_kernel<<<(NN + 3) / 4, 256, 0, stream>>>(h2, as2, ad2, cnt, csr, bias2, out);
}

// Round 10
// 227.809 us; speedup vs baseline: 1.0857x; 1.0294x over previous
//
#include <hip/hip_runtime.h>

#define NN 20000      // nodes
#define FIN 256
#define D1 1024       // H1*C1 = 8*128
#define NH 8
#define C2 128
#define CAP 64        // padded CSR bucket capacity (max degree ~35 incl. self-loop)

typedef unsigned short u16;
typedef unsigned char u8;
typedef __attribute__((ext_vector_type(8))) short bf16x8;
typedef __attribute__((ext_vector_type(4))) float f32x4;
typedef __attribute__((ext_vector_type(2))) float f32x2;

// ---------- bf16 helpers ----------
__device__ __forceinline__ float bf2f(u16 u) {
    return __uint_as_float(((unsigned int)u) << 16);
}
__device__ __forceinline__ u16 f2bf(float f) {
    unsigned int u = __float_as_uint(f);
    u += 0x7FFFu + ((u >> 16) & 1u);   // round-to-nearest-even
    return (u16)(u >> 16);
}
// ---------- fp8 e4m3 (OCP) helpers via HW converts ----------
__device__ __forceinline__ u8 f2fp8(float v) {
    int q = __builtin_amdgcn_cvt_pk_fp8_f32(v, v, 0, false);
    return (u8)(q & 0xFF);
}

// butterfly reductions: every lane ends with the result
__device__ __forceinline__ float bred_max(float v) {
    #pragma unroll
    for (int o = 32; o > 0; o >>= 1) v = fmaxf(v, __shfl_xor(v, o, 64));
    return v;
}
__device__ __forceinline__ float bred_sum(float v) {
    #pragma unroll
    for (int o = 32; o > 0; o >>= 1) v += __shfl_xor(v, o, 64);
    return v;
}

// async global->LDS, 16B per lane (global_load_lds_dwordx4)
typedef const __attribute__((address_space(1))) unsigned int* as1_u32p;
typedef __attribute__((address_space(3))) unsigned int* as3_u32p;
__device__ __forceinline__ void gload_lds16(const void* g, void* l) {
    __builtin_amdgcn_global_load_lds((as1_u32p)g, (as3_u32p)l, 16, 0, 0);
}

// ---------- fused prep: cast x->bf16 | transpose W1/W2 | CSR fill ----------
// cnt is zeroed by hipMemsetAsync BEFORE this kernel, so the fill part can
// run concurrently with the cast/transpose blocks (disjoint data).
// Block ranges: [0,5000) cast, [5000,5256) W1t, [5256,5384) W2t,
// [5384, 5384+ceil((E+NN)/256)) edge fill.
__global__ __launch_bounds__(256) void prep_kernel(const float* __restrict__ x,
                                                   u16* __restrict__ xb,
                                                   const float* __restrict__ W1,
                                                   u16* __restrict__ w1t,
                                                   const float* __restrict__ W2,
                                                   u16* __restrict__ w2t,
                                                   const int* __restrict__ ei,
                                                   int E,
                                                   int* __restrict__ cnt,
                                                   int* __restrict__ csr) {
    __shared__ float tile[32][33];
    const int b = blockIdx.x, tid = threadIdx.x;
    if (b < 5000) {
        int i = (b * 256 + tid) * 4;
        if (i < NN * FIN) {
            float4 v = *(const float4*)(x + i);
            ushort4 o;
            o.x = f2bf(v.x); o.y = f2bf(v.y); o.z = f2bf(v.z); o.w = f2bf(v.w);
            *(ushort4*)(xb + i) = o;
        }
        return;
    }
    if (b < 5384) {
        const float* in; u16* out; int R, C, bx, by;
        if (b < 5256) {
            int q = b - 5000;                 // W1: [FIN x D1] -> [D1 x FIN]
            in = W1; out = w1t; R = FIN; C = D1;
            bx = (q & 31) * 32; by = (q >> 5) * 32;
        } else {
            int q = b - 5256;                 // W2: [D1 x C2] -> [C2 x D1]
            in = W2; out = w2t; R = D1; C = C2;
            bx = (q & 3) * 32; by = (q >> 2) * 32;
        }
        int tx = tid & 31, ty = tid >> 5;     // 32x8
        #pragma unroll
        for (int i = 0; i < 32; i += 8)
            tile[ty + i][tx] = in[(size_t)(by + ty + i) * C + bx + tx];
        __syncthreads();
        #pragma unroll
        for (int i = 0; i < 32; i += 8)
            out[(size_t)(bx + ty + i) * R + by + tx] = f2bf(tile[tx][ty + i]);
        return;
    }
    // ---- padded-bucket CSR fill (self-loops appended) ----
    int j = (b - 5384) * 256 + tid;
    if (j >= E + NN) return;
    int s, d;
    if (j < E) { s = ei[j]; d = ei[E + j]; }
    else { s = j - E; d = j - E; }
    int pos = atomicAdd(&cnt[d], 1);
    if (pos >= CAP) return;   // safety net (never expected)
    csr[d * CAP + pos] = s;
}

// ---------- bf16 MFMA GEMM, 2-phase double-buffered, generic BK ----------
// C[MxN] = A[MxK] * Bt[NxK]^T.  Per K-step: issue next tile's
// global_load_lds into buf^1, then ds_read+MFMA on buf, then ONE
// __syncthreads. Fused per-head attention-dot epilogue.
// OMODE 1: bf16 C out (layer 2; 2D grid, head 0).
// OMODE 2: fp8 e4m3 C out (layer 1; 1D grid with XCD-COHORT SWIZZLE:
//   id = grp*64 + head*8 + (xs&7), so the 8 head-blocks sharing one
//   A-tile have ids congruent mod 8 -> SAME XCD -> the 64KB A-tile is
//   fetched into that XCD's L2 once and hit by the other 7 heads.
//   Default linearization put them on 8 different XCDs = 8x re-fetch
//   of the whole 10MB A matrix through L3/HBM.)
#define G_STAGE(BUF, K0)                                                   \
    {                                                                      \
        constexpr int CPR = BK / 8;   /* 16B chunks per row */             \
        _Pragma("unroll")                                                  \
        for (int i = 0; i < BM * BK / 8 / 256; i++) {                      \
            int c = tid + i * 256;                                         \
            int r = c / CPR, ko = (c % CPR) * 8;                           \
            int gr = row0 + r; if (gr >= M) gr = M - 1;                    \
            gload_lds16(A + (size_t)gr * K + (K0) + ko,                    \
                        &ldsA[BUF][c * 8]);                                \
        }                                                                  \
        _Pragma("unroll")                                                  \
        for (int i = 0; i < 128 * BK / 8 / 256; i++) {                     \
            int c = tid + i * 256;                                         \
            int n = c / CPR, ko = (c % CPR) * 8;                           \
            gload_lds16(Bt + (size_t)(col0 + n) * K + (K0) + ko,           \
                        &ldsB[BUF][c * 8]);                                \
        }                                                                  \
    }

template <int BM, int BK, int OMODE>
__global__ __launch_bounds__(256) void gemm_mfma(const u16* __restrict__ A,
                                                 const u16* __restrict__ Bt,
                                                 void* __restrict__ C,
                                                 const float* __restrict__ attS,
                                                 const float* __restrict__ attD,
                                                 float* __restrict__ as_out,
                                                 float* __restrict__ ad_out,
                                                 int NHo,
                                                 int M, int N, int K) {
    constexpr int TM = BM / 32;            // 16-tiles per wave along m
    constexpr int KK = BK / 32;            // MFMA k-substeps per K-step
    __shared__ u16 ldsA[2][BM * BK];
    __shared__ u16 ldsB[2][128 * BK];
    __shared__ float asb[BM], adb[BM];
    const int tid = threadIdx.x;
    const int lane = tid & 63, w = tid >> 6;
    const int wr = w >> 1, wc = w & 1;
    int row0, col0, head;
    if (OMODE == 2) {
        // XCD-cohort decode: xs = (grp<<3)|(id&7), head = (id>>3)&7
        int id = blockIdx.x;
        int xs = ((id >> 6) << 3) | (id & 7);
        head = (id >> 3) & 7;
        if (xs >= (M + BM - 1) / BM) return;   // hole blocks (uniform exit)
        row0 = xs * BM; col0 = head * 128;
    } else {
        row0 = blockIdx.x * BM; col0 = 0; head = 0;
    }
    const int l15 = lane & 15, quad = lane >> 4;

    for (int t = tid; t < BM; t += 256) { asb[t] = 0.f; adb[t] = 0.f; }

    f32x4 acc[TM][4];
    #pragma unroll
    for (int i = 0; i < TM; i++)
        #pragma unroll
        for (int j = 0; j < 4; j++)
            acc[i][j] = (f32x4){0.f, 0.f, 0.f, 0.f};

    G_STAGE(0, 0)
    __syncthreads();
    int cur = 0;
    for (int k0 = 0; k0 < K; k0 += BK) {
        if (k0 + BK < K) {
            G_STAGE(cur ^ 1, k0 + BK)              // prefetch next K-tile
            __builtin_amdgcn_sched_barrier(0);     // keep issue above compute
        }
        bf16x8 af[TM][KK], bfr[KK][4];
        #pragma unroll
        for (int i = 0; i < TM; i++) {
            int m = wr * (BM / 2) + i * 16 + l15;
            #pragma unroll
            for (int kk = 0; kk < KK; kk++)
                af[i][kk] = *(const bf16x8*)(&ldsA[cur][m * BK + kk * 32 + quad * 8]);
        }
        #pragma unroll
        for (int j = 0; j < 4; j++) {
            int n = wc * 64 + j * 16 + l15;
            #pragma unroll
            for (int kk = 0; kk < KK; kk++)
                bfr[kk][j] = *(const bf16x8*)(&ldsB[cur][n * BK + kk * 32 + quad * 8]);
        }
        #pragma unroll
        for (int i = 0; i < TM; i++)
            #pragma unroll
            for (int kk = 0; kk < KK; kk++)
                #pragma unroll
                for (int j = 0; j < 4; j++)
                    acc[i][j] = __builtin_amdgcn_mfma_f32_16x16x32_bf16(af[i][kk], bfr[kk][j], acc[i][j], 0, 0, 0);
        __syncthreads();                           // buf^1 staged + all reads done
        cur ^= 1;
    }
    // ---- C write (fp8 for layer1, bf16 for layer2) ----
    #pragma unroll
    for (int i = 0; i < TM; i++) {
        #pragma unroll
        for (int j = 0; j < 4; j++) {
            #pragma unroll
            for (int r = 0; r < 4; r++) {
                int row = row0 + wr * (BM / 2) + i * 16 + quad * 4 + r;
                int col = col0 + wc * 64 + j * 16 + l15;
                if (row < M) {
                    float v = acc[i][j][r];
                    if (OMODE == 1)
                        ((u16*)C)[(size_t)row * N + col] = f2bf(v);
                    else
                        ((u8*)C)[(size_t)row * N + col] = f2fp8(v);
                }
            }
        }
    }
    // ---- fused per-row attention dots for this head ----
    float attS_r[4], attD_r[4];
    #pragma unroll
    for (int j = 0; j < 4; j++) {
        int col = wc * 64 + j * 16 + l15;
        attS_r[j] = attS[head * 128 + col];
        attD_r[j] = attD[head * 128 + col];
    }
    #pragma unroll
    for (int i = 0; i < TM; i++) {
        #pragma unroll
        for (int r = 0; r < 4; r++) {
            float ps = 0.f, pd = 0.f;
            #pragma unroll
            for (int j = 0; j < 4; j++) {
                float v = acc[i][j][r];
                ps = fmaf(v, attS_r[j], ps);
                pd = fmaf(v, attD_r[j], pd);
            }
            #pragma unroll
            for (int o = 1; o < 16; o <<= 1) {
                ps += __shfl_xor(ps, o, 64);
                pd += __shfl_xor(pd, o, 64);
            }
            if (l15 == 0) {
                int row = wr * (BM / 2) + i * 16 + quad * 4 + r;
                atomicAdd(&asb[row], ps);
                atomicAdd(&adb[row], pd);
            }
        }
    }
    __syncthreads();
    for (int t = tid; t < BM; t += 256) {
        int row = row0 + t;
        if (row < M) {
            as_out[(size_t)row * NHo + head] = asb[t];
            ad_out[(size_t)row * NHo + head] = adb[t];
        }
    }
}

// ---------- layer-1 softmax-aggregate + ELU (WIDE, R4/R7 structure) ----------
// ONE WAVE per dst, 16 ch/lane covering all 1024 ch; GROUP=8 depth-2
// ping-pong; inline per-edge as1 weight load (L2-resident 640KB table).
// Fabric-bound at ~3.4-3.9 TB/s (measured R4/R7/R9); latency and VALU
// trims don't move it (R3/R5/R6); single dispatch (R8 split cost ~17us).
#define A1_FETCH8(E0, Q, P)                                                   \
    {                                                                         \
        _Pragma("unroll")                                                     \
        for (int u = 0; u < 8; u++) {                                         \
            int e = (E0) + u;             /* e <= 63 < CAP always */          \
            int s = __builtin_amdgcn_readlane(idx, e);                        \
            s = s < 0 ? 0 : (s > NN - 1 ? NN - 1 : s);   /* SALU clamp */     \
            Q[u] = *(const uint4*)(h1q + (size_t)s * D1 + c0);                \
            P[u] = as1[s * NH + h];       /* L2-hit 4B; masked at PROC */     \
        }                                                                     \
        __builtin_amdgcn_sched_barrier(0);                                    \
    }
#define A1_PROC8(E0, Q, P)                                                    \
    {                                                                         \
        _Pragma("unroll")                                                     \
        for (int u = 0; u < 8; u++) {                                         \
            float ev = (P)[u] + adv;                                          \
            ev = ev > 0.f ? ev : 0.2f * ev;           /* LeakyReLU(0.2) */    \
            float pp = ((E0) + u < deg) ? __expf(ev) : 0.f;                   \
            den += pp;                                                        \
            f32x2 pv2 = {pp, pp};                                             \
            acc[0] += pv2 * __builtin_amdgcn_cvt_pk_f32_fp8((Q)[u].x, false); \
            acc[1] += pv2 * __builtin_amdgcn_cvt_pk_f32_fp8((Q)[u].x, true);  \
            acc[2] += pv2 * __builtin_amdgcn_cvt_pk_f32_fp8((Q)[u].y, false); \
            acc[3] += pv2 * __builtin_amdgcn_cvt_pk_f32_fp8((Q)[u].y, true);  \
            acc[4] += pv2 * __builtin_amdgcn_cvt_pk_f32_fp8((Q)[u].z, false); \
            acc[5] += pv2 * __builtin_amdgcn_cvt_pk_f32_fp8((Q)[u].z, true);  \
            acc[6] += pv2 * __builtin_amdgcn_cvt_pk_f32_fp8((Q)[u].w, false); \
            acc[7] += pv2 * __builtin_amdgcn_cvt_pk_f32_fp8((Q)[u].w, true);  \
        }                                                                     \
    }

__global__ __launch_bounds__(256) void agg1_kernel(const u8* __restrict__ h1q,
                                                   const float* __restrict__ as1,
                                                   const float* __restrict__ ad1,
                                                   const int* __restrict__ cnt,
                                                   const int* __restrict__ csr,
                                                   const float* __restrict__ bias1,
                                                   u16* __restrict__ x2) {
    const int tid = threadIdx.x;
    const int lane = tid & 63;
    const int dst = (blockIdx.x << 2) + (tid >> 6);
    const int c0 = lane * 16;               // 16 channels per lane
    const int h = lane >> 3;                // head (all 16 lane-channels same head)
    const int base = dst * CAP;

    int idx = csr[base + lane];                     // unclamped: || with cnt load
    const int deg = __builtin_amdgcn_readfirstlane(max(1, min(cnt[dst], CAP)));
    const float adv = ad1[dst * NH + h];            // per-head dst term

    f32x2 acc[8];
    #pragma unroll
    for (int k = 0; k < 8; k++) acc[k] = (f32x2){0.f, 0.f};
    float den = 0.f;

    const int nit = (deg + 7) >> 3;                 // groups of 8
    uint4 qa[8], qb[8];
    float pa[8], pb[8];
    A1_FETCH8(0, qa, pa)
    int g = 0;
    for (; g + 2 < nit; g += 2) {                   // ping-pong
        A1_FETCH8((g + 1) * 8, qb, pb)
        A1_PROC8(g * 8, qa, pa)
        A1_FETCH8((g + 2) * 8, qa, pa)
        A1_PROC8((g + 1) * 8, qb, pb)
    }
    if (g + 1 < nit) {
        A1_FETCH8((g + 1) * 8, qb, pb)
        A1_PROC8(g * 8, qa, pa)
        A1_PROC8((g + 1) * 8, qb, pb)
    } else {
        A1_PROC8(g * 8, qa, pa)
    }

    float inv = 1.f / (den + 1e-16f);
    u16 ov[16];
    #pragma unroll
    for (int k = 0; k < 8; k++) {
        float a0 = acc[k][0] * inv + bias1[c0 + 2 * k];
        float a1 = acc[k][1] * inv + bias1[c0 + 2 * k + 1];
        a0 = a0 > 0.f ? a0 : (__expf(a0) - 1.f);   // ELU (abs err ~1e-7, tol 0.03)
        a1 = a1 > 0.f ? a1 : (__expf(a1) - 1.f);
        ov[2 * k] = f2bf(a0);
        ov[2 * k + 1] = f2bf(a1);
    }
    *(uint4*)(x2 + (size_t)dst * D1 + c0) = *(const uint4*)ov;
    *(uint4*)(x2 + (size_t)dst * D1 + c0 + 8) = *(const uint4*)(ov + 8);
}

// ---------- layer-2 softmax-aggregate + log_softmax, lean PROC (R6) ----------
// ONE WAVE per dst; hoisted den / pre-masked pl / scalar-fmaf.
#define A2_FETCH8(E0, Q)                                                      \
    {                                                                         \
        _Pragma("unroll")                                                     \
        for (int u = 0; u < 8; u++) {                                         \
            int s = __builtin_amdgcn_readlane(idx, (E0) + u);                 \
            s = s < 0 ? 0 : (s > NN - 1 ? NN - 1 : s);                        \
            Q[u] = *(const unsigned int*)(h2 + (size_t)s * C2 + lane2);       \
        }                                                                     \
        __builtin_amdgcn_sched_barrier(0);                                    \
    }
#define A2_PROC8(E0, Q)                                                       \
    {                                                                         \
        _Pragma("unroll")                                                     \
        for (int u = 0; u < 8; u++) {                                         \
            float pp = __uint_as_float(__builtin_amdgcn_readlane(             \
                __float_as_uint(pl), (E0) + u));                              \
            float f0 = __uint_as_float((Q)[u] << 16);                         \
            float f1 = __uint_as_float((Q)[u] & 0xFFFF0000u);                 \
            a0 = fmaf(pp, f0, a0);                                            \
            a1 = fmaf(pp, f1, a1);                                            \
        }                                                                     \
    }

__global__ __launch_bounds__(256) void agg2_kernel(const u16* __restrict__ h2,
                                                   const float* __restrict__ as2,
                                                   const float* __restrict__ ad2,
                                                   const int* __restrict__ cnt,
                                                   const int* __restrict__ csr,
                                                   const float* __restrict__ bias2,
                                                   float* __restrict__ out) {
    const int tid = threadIdx.x;
    const int lane = tid & 63;
    const int dst = (blockIdx.x << 2) + __builtin_amdgcn_readfirstlane(tid >> 6);
    const int base = dst * CAP;
    const int lane2 = lane * 2;

    int idx = csr[base + lane];                 // coalesced; || with cnt
    const int deg = max(1, min(cnt[dst], CAP)); // scalar
    const float adv = ad2[dst];
    int idxc = idx < 0 ? 0 : (idx > NN - 1 ? NN - 1 : idx);
    float ev = as2[idxc] + adv;                 // random 4B within 80 KB (L2)
    ev = ev > 0.f ? ev : 0.2f * ev;
    float pl = (lane < deg) ? __expf(ev) : 0.f; // masked ONCE
    float den = bred_sum(pl);                   // hoisted

    float a0 = 0.f, a1 = 0.f;

    const int nit = (deg + 7) >> 3;
    unsigned int qa[8], qb[8];
    A2_FETCH8(0, qa)
    int g = 0;
    for (; g + 2 < nit; g += 2) {
        A2_FETCH8((g + 1) * 8, qb)
        A2_PROC8(g * 8, qa)
        A2_FETCH8((g + 2) * 8, qa)
        A2_PROC8((g + 1) * 8, qb)
    }
    if (g + 1 < nit) {
        A2_FETCH8((g + 1) * 8, qb)
        A2_PROC8(g * 8, qa)
        A2_PROC8((g + 1) * 8, qb)
    } else {
        A2_PROC8(g * 8, qa)
    }

    float inv = 1.f / (den + 1e-16f);
    float l0 = a0 * inv + bias2[lane2];
    float l1 = a1 * inv + bias2[lane2 + 1];
    // log_softmax over the wave's 128 channels
    float m = bred_max(fmaxf(l0, l1));
    float ex = bred_sum(__expf(l0 - m) + __expf(l1 - m));
    float lse = m + __logf(ex);
    float2 ov = {l0 - lse, l1 - lse};
    *(float2*)(out + (size_t)dst * C2 + lane2) = ov;
}

extern "C" void kernel_launch(void* const* d_in, const int* in_sizes, int n_in,
                              void* d_out, int out_size, void* d_ws, size_t ws_size,
                              hipStream_t stream) {
    const float* x        = (const float*)d_in[0];
    const int*   ei       = (const int*)d_in[1];
    const float* W1       = (const float*)d_in[2];
    const float* att_src1 = (const float*)d_in[3];
    const float* att_dst1 = (const float*)d_in[4];
    const float* bias1    = (const float*)d_in[5];
    const float* W2       = (const float*)d_in[6];
    const float* att_src2 = (const float*)d_in[7];
    const float* att_dst2 = (const float*)d_in[8];
    const float* bias2    = (const float*)d_in[9];
    float* out = (float*)d_out;
    const int E = in_sizes[1] / 2;

    char* ws = (char*)d_ws;
    size_t off = 0;
    auto alloc = [&](size_t b) {
        void* p = ws + off;
        off += (b + 255) & ~(size_t)255;
        return p;
    };
    u8*  h1q  = (u8*)alloc((size_t)NN * D1);
    u16* x2   = (u16*)alloc((size_t)NN * D1 * 2);
    u16* h2   = (u16*)alloc((size_t)NN * C2 * 2);
    u16* xb   = (u16*)alloc((size_t)NN * FIN * 2);
    u16* w1t  = (u16*)alloc((size_t)D1 * FIN * 2);
    u16* w2t  = (u16*)alloc((size_t)C2 * D1 * 2);
    float* as1 = (float*)alloc((size_t)NN * NH * 4);
    float* ad1 = (float*)alloc((size_t)NN * NH * 4);
    float* as2 = (float*)alloc((size_t)NN * 4);
    float* ad2 = (float*)alloc((size_t)NN * 4);
    int* cnt  = (int*)alloc((size_t)NN * 4);
    int* csr  = (int*)alloc((size_t)NN * CAP * 4);

    // zero cnt up front; fused prep then casts x, transposes W1/W2 AND
    // fills the CSR buckets (fill overlaps the BW-heavy cast blocks)
    hipMemsetAsync(cnt, 0, (size_t)NN * 4, stream);
    const int FILL_BLOCKS = (E + NN + 255) / 256;
    prep_kernel<<<5384 + FILL_BLOCKS, 256, 0, stream>>>(x, xb, W1, w1t, W2, w2t,
                                                        ei, E, cnt, csr);

    // layer 1 GEMM: h1q fp8 + fused per-head as1/ad1. XCD-cohort grid:
    // 157 row-tiles -> 20 groups of 8 slots x 8 heads = 1280 blocks
    // (24 holes exit early); heads of one row-tile share an XCD's L2.
    gemm_mfma<128, 32, 2><<<1280, 256, 0, stream>>>(
        xb, w1t, h1q, att_src1, att_dst1, as1, ad1, NH, NN, D1, FIN);
    // 1 wave per dst: 20000 waves = 5000 blocks (single dispatch)
    agg1_kernel<<<(NN + 3) / 4, 256, 0, stream>>>(h1q, as1, ad1, cnt, csr,
                                                  bias1, x2);
    // layer 2 GEMM: h2 bf16 + fused as2/ad2 (R7-proven BM=64/BK=32)
    gemm_mfma<64, 32, 1><<<dim3((NN + 63) / 64, 1), 256, 0, stream>>>(
        x2, w2t, h2, att_src2, att_dst2, as2, ad2, 1, NN, C2, D1);
    agg2_kernel<<<(NN + 3) / 4, 256, 0, stream>>>(h2, as2, ad2, cnt, csr, bias2, out);
}

// Round 11
// 227.467 us; speedup vs baseline: 1.0873x; 1.0015x over previous
//
#include <hip/hip_runtime.h>

#define NN 20000      // nodes
#define FIN 256
#define D1 1024       // H1*C1 = 8*128
#define NH 8
#define C2 128
#define CAP 64        // padded CSR bucket capacity (max degree ~35 incl. self-loop)

typedef unsigned short u16;
typedef unsigned char u8;
typedef __attribute__((ext_vector_type(8))) short bf16x8;
typedef __attribute__((ext_vector_type(4))) float f32x4;
typedef __attribute__((ext_vector_type(2))) float f32x2;

// ---------- bf16 helpers ----------
__device__ __forceinline__ float bf2f(u16 u) {
    return __uint_as_float(((unsigned int)u) << 16);
}
__device__ __forceinline__ u16 f2bf(float f) {
    unsigned int u = __float_as_uint(f);
    u += 0x7FFFu + ((u >> 16) & 1u);   // round-to-nearest-even
    return (u16)(u >> 16);
}
// ---------- fp8 e4m3 (OCP) helpers via HW converts ----------
__device__ __forceinline__ u8 f2fp8(float v) {
    int q = __builtin_amdgcn_cvt_pk_fp8_f32(v, v, 0, false);
    return (u8)(q & 0xFF);
}

// butterfly reductions: every lane ends with the result
__device__ __forceinline__ float bred_max(float v) {
    #pragma unroll
    for (int o = 32; o > 0; o >>= 1) v = fmaxf(v, __shfl_xor(v, o, 64));
    return v;
}
__device__ __forceinline__ float bred_sum(float v) {
    #pragma unroll
    for (int o = 32; o > 0; o >>= 1) v += __shfl_xor(v, o, 64);
    return v;
}

// async global->LDS, 16B per lane (global_load_lds_dwordx4)
typedef const __attribute__((address_space(1))) unsigned int* as1_u32p;
typedef __attribute__((address_space(3))) unsigned int* as3_u32p;
__device__ __forceinline__ void gload_lds16(const void* g, void* l) {
    __builtin_amdgcn_global_load_lds((as1_u32p)g, (as3_u32p)l, 16, 0, 0);
}

// ---------- fused prep: cast x->bf16 | transpose W1/W2 | CSR fill ----------
// cnt is zeroed by hipMemsetAsync BEFORE this kernel, so the fill part can
// run concurrently with the cast/transpose blocks (disjoint data).
// Block ranges: [0,5000) cast, [5000,5256) W1t, [5256,5384) W2t,
// [5384, 5384+ceil((E+NN)/256)) edge fill.
__global__ __launch_bounds__(256) void prep_kernel(const float* __restrict__ x,
                                                   u16* __restrict__ xb,
                                                   const float* __restrict__ W1,
                                                   u16* __restrict__ w1t,
                                                   const float* __restrict__ W2,
                                                   u16* __restrict__ w2t,
                                                   const int* __restrict__ ei,
                                                   int E,
                                                   int* __restrict__ cnt,
                                                   int* __restrict__ csr) {
    __shared__ float tile[32][33];
    const int b = blockIdx.x, tid = threadIdx.x;
    if (b < 5000) {
        int i = (b * 256 + tid) * 4;
        if (i < NN * FIN) {
            float4 v = *(const float4*)(x + i);
            ushort4 o;
            o.x = f2bf(v.x); o.y = f2bf(v.y); o.z = f2bf(v.z); o.w = f2bf(v.w);
            *(ushort4*)(xb + i) = o;
        }
        return;
    }
    if (b < 5384) {
        const float* in; u16* out; int R, C, bx, by;
        if (b < 5256) {
            int q = b - 5000;                 // W1: [FIN x D1] -> [D1 x FIN]
            in = W1; out = w1t; R = FIN; C = D1;
            bx = (q & 31) * 32; by = (q >> 5) * 32;
        } else {
            int q = b - 5256;                 // W2: [D1 x C2] -> [C2 x D1]
            in = W2; out = w2t; R = D1; C = C2;
            bx = (q & 3) * 32; by = (q >> 2) * 32;
        }
        int tx = tid & 31, ty = tid >> 5;     // 32x8
        #pragma unroll
        for (int i = 0; i < 32; i += 8)
            tile[ty + i][tx] = in[(size_t)(by + ty + i) * C + bx + tx];
        __syncthreads();
        #pragma unroll
        for (int i = 0; i < 32; i += 8)
            out[(size_t)(bx + ty + i) * R + by + tx] = f2bf(tile[tx][ty + i]);
        return;
    }
    // ---- padded-bucket CSR fill (self-loops appended) ----
    int j = (b - 5384) * 256 + tid;
    if (j >= E + NN) return;
    int s, d;
    if (j < E) { s = ei[j]; d = ei[E + j]; }
    else { s = j - E; d = j - E; }
    int pos = atomicAdd(&cnt[d], 1);
    if (pos >= CAP) return;   // safety net (never expected)
    csr[d * CAP + pos] = s;
}

// ---------- bf16 MFMA GEMM, 2-phase double-buffered, generic BK ----------
// C[MxN] = A[MxK] * Bt[NxK]^T.  Per K-step: issue next tile's
// global_load_lds into buf^1, then ds_read+MFMA on buf, then ONE
// __syncthreads. Fused per-head attention-dot epilogue.
// OMODE 1: bf16 C out (layer 2; 2D grid, head 0).
// OMODE 2: fp8 e4m3 C out (layer 1; 1D grid with XCD-COHORT SWIZZLE:
//   the 8 head-blocks sharing one A-tile have ids congruent mod 8 ->
//   same XCD -> the 64KB A-tile lands in that XCD's L2 once.)
#define G_STAGE(BUF, K0)                                                   \
    {                                                                      \
        constexpr int CPR = BK / 8;   /* 16B chunks per row */             \
        _Pragma("unroll")                                                  \
        for (int i = 0; i < BM * BK / 8 / 256; i++) {                      \
            int c = tid + i * 256;                                         \
            int r = c / CPR, ko = (c % CPR) * 8;                           \
            int gr = row0 + r; if (gr >= M) gr = M - 1;                    \
            gload_lds16(A + (size_t)gr * K + (K0) + ko,                    \
                        &ldsA[BUF][c * 8]);                                \
        }                                                                  \
        _Pragma("unroll")                                                  \
        for (int i = 0; i < 128 * BK / 8 / 256; i++) {                     \
            int c = tid + i * 256;                                         \
            int n = c / CPR, ko = (c % CPR) * 8;                           \
            gload_lds16(Bt + (size_t)(col0 + n) * K + (K0) + ko,           \
                        &ldsB[BUF][c * 8]);                                \
        }                                                                  \
    }

template <int BM, int BK, int OMODE>
__global__ __launch_bounds__(256) void gemm_mfma(const u16* __restrict__ A,
                                                 const u16* __restrict__ Bt,
                                                 void* __restrict__ C,
                                                 const float* __restrict__ attS,
                                                 const float* __restrict__ attD,
                                                 float* __restrict__ as_out,
                                                 float* __restrict__ ad_out,
                                                 int NHo,
                                                 int M, int N, int K) {
    constexpr int TM = BM / 32;            // 16-tiles per wave along m
    constexpr int KK = BK / 32;            // MFMA k-substeps per K-step
    __shared__ u16 ldsA[2][BM * BK];
    __shared__ u16 ldsB[2][128 * BK];
    __shared__ float asb[BM], adb[BM];
    const int tid = threadIdx.x;
    const int lane = tid & 63, w = tid >> 6;
    const int wr = w >> 1, wc = w & 1;
    int row0, col0, head;
    if (OMODE == 2) {
        // XCD-cohort decode: xs = (grp<<3)|(id&7), head = (id>>3)&7
        int id = blockIdx.x;
        int xs = ((id >> 6) << 3) | (id & 7);
        head = (id >> 3) & 7;
        if (xs >= (M + BM - 1) / BM) return;   // hole blocks (uniform exit)
        row0 = xs * BM; col0 = head * 128;
    } else {
        row0 = blockIdx.x * BM; col0 = 0; head = 0;
    }
    const int l15 = lane & 15, quad = lane >> 4;

    for (int t = tid; t < BM; t += 256) { asb[t] = 0.f; adb[t] = 0.f; }

    f32x4 acc[TM][4];
    #pragma unroll
    for (int i = 0; i < TM; i++)
        #pragma unroll
        for (int j = 0; j < 4; j++)
            acc[i][j] = (f32x4){0.f, 0.f, 0.f, 0.f};

    G_STAGE(0, 0)
    __syncthreads();
    int cur = 0;
    for (int k0 = 0; k0 < K; k0 += BK) {
        if (k0 + BK < K) {
            G_STAGE(cur ^ 1, k0 + BK)              // prefetch next K-tile
            __builtin_amdgcn_sched_barrier(0);     // keep issue above compute
        }
        bf16x8 af[TM][KK], bfr[KK][4];
        #pragma unroll
        for (int i = 0; i < TM; i++) {
            int m = wr * (BM / 2) + i * 16 + l15;
            #pragma unroll
            for (int kk = 0; kk < KK; kk++)
                af[i][kk] = *(const bf16x8*)(&ldsA[cur][m * BK + kk * 32 + quad * 8]);
        }
        #pragma unroll
        for (int j = 0; j < 4; j++) {
            int n = wc * 64 + j * 16 + l15;
            #pragma unroll
            for (int kk = 0; kk < KK; kk++)
                bfr[kk][j] = *(const bf16x8*)(&ldsB[cur][n * BK + kk * 32 + quad * 8]);
        }
        #pragma unroll
        for (int i = 0; i < TM; i++)
            #pragma unroll
            for (int kk = 0; kk < KK; kk++)
                #pragma unroll
                for (int j = 0; j < 4; j++)
                    acc[i][j] = __builtin_amdgcn_mfma_f32_16x16x32_bf16(af[i][kk], bfr[kk][j], acc[i][j], 0, 0, 0);
        __syncthreads();                           // buf^1 staged + all reads done
        cur ^= 1;
    }
    // ---- C write (fp8 for layer1, bf16 for layer2) ----
    #pragma unroll
    for (int i = 0; i < TM; i++) {
        #pragma unroll
        for (int j = 0; j < 4; j++) {
            #pragma unroll
            for (int r = 0; r < 4; r++) {
                int row = row0 + wr * (BM / 2) + i * 16 + quad * 4 + r;
                int col = col0 + wc * 64 + j * 16 + l15;
                if (row < M) {
                    float v = acc[i][j][r];
                    if (OMODE == 1)
                        ((u16*)C)[(size_t)row * N + col] = f2bf(v);
                    else
                        ((u8*)C)[(size_t)row * N + col] = f2fp8(v);
                }
            }
        }
    }
    // ---- fused per-row attention dots for this head ----
    float attS_r[4], attD_r[4];
    #pragma unroll
    for (int j = 0; j < 4; j++) {
        int col = wc * 64 + j * 16 + l15;
        attS_r[j] = attS[head * 128 + col];
        attD_r[j] = attD[head * 128 + col];
    }
    #pragma unroll
    for (int i = 0; i < TM; i++) {
        #pragma unroll
        for (int r = 0; r < 4; r++) {
            float ps = 0.f, pd = 0.f;
            #pragma unroll
            for (int j = 0; j < 4; j++) {
                float v = acc[i][j][r];
                ps = fmaf(v, attS_r[j], ps);
                pd = fmaf(v, attD_r[j], pd);
            }
            #pragma unroll
            for (int o = 1; o < 16; o <<= 1) {
                ps += __shfl_xor(ps, o, 64);
                pd += __shfl_xor(pd, o, 64);
            }
            if (l15 == 0) {
                int row = wr * (BM / 2) + i * 16 + quad * 4 + r;
                atomicAdd(&asb[row], ps);
                atomicAdd(&adb[row], pd);
            }
        }
    }
    __syncthreads();
    for (int t = tid; t < BM; t += 256) {
        int row = row0 + t;
        if (row < M) {
            as_out[(size_t)row * NHo + head] = asb[t];
            ad_out[(size_t)row * NHo + head] = adb[t];
        }
    }
}

// ---------- layer-1 softmax-aggregate + ELU (WIDE, 1-WAVE BLOCKS) ----------
// ONE 64-THREAD BLOCK per dst (was 4 dsts per 256-thread block): block
// retires as soon as ITS dst finishes, so the scheduler backfills
// immediately -- removes the max-of-4 degree imbalance (Poisson deg
// mean~17, E[max4]~23 -> ~30% wave-slot waste) behind R10's 24%
// occupancy. GROUP=8 depth-2 ping-pong; inline per-edge as1 weight
// (L2-resident 640KB table). Fabric band 3.4-3.9 TB/s (R4/R7/R9/R10).
#define A1_FETCH8(E0, Q, P)                                                   \
    {                                                                         \
        _Pragma("unroll")                                                     \
        for (int u = 0; u < 8; u++) {                                         \
            int e = (E0) + u;             /* e <= 63 < CAP always */          \
            int s = __builtin_amdgcn_readlane(idx, e);                        \
            s = s < 0 ? 0 : (s > NN - 1 ? NN - 1 : s);   /* SALU clamp */     \
            Q[u] = *(const uint4*)(h1q + (size_t)s * D1 + c0);                \
            P[u] = as1[s * NH + h];       /* L2-hit 4B; masked at PROC */     \
        }                                                                     \
        __builtin_amdgcn_sched_barrier(0);                                    \
    }
#define A1_PROC8(E0, Q, P)                                                    \
    {                                                                         \
        _Pragma("unroll")                                                     \
        for (int u = 0; u < 8; u++) {                                         \
            float ev = (P)[u] + adv;                                          \
            ev = ev > 0.f ? ev : 0.2f * ev;           /* LeakyReLU(0.2) */    \
            float pp = ((E0) + u < deg) ? __expf(ev) : 0.f;                   \
            den += pp;                                                        \
            f32x2 pv2 = {pp, pp};                                             \
            acc[0] += pv2 * __builtin_amdgcn_cvt_pk_f32_fp8((Q)[u].x, false); \
            acc[1] += pv2 * __builtin_amdgcn_cvt_pk_f32_fp8((Q)[u].x, true);  \
            acc[2] += pv2 * __builtin_amdgcn_cvt_pk_f32_fp8((Q)[u].y, false); \
            acc[3] += pv2 * __builtin_amdgcn_cvt_pk_f32_fp8((Q)[u].y, true);  \
            acc[4] += pv2 * __builtin_amdgcn_cvt_pk_f32_fp8((Q)[u].z, false); \
            acc[5] += pv2 * __builtin_amdgcn_cvt_pk_f32_fp8((Q)[u].z, true);  \
            acc[6] += pv2 * __builtin_amdgcn_cvt_pk_f32_fp8((Q)[u].w, false); \
            acc[7] += pv2 * __builtin_amdgcn_cvt_pk_f32_fp8((Q)[u].w, true);  \
        }                                                                     \
    }

__global__ __launch_bounds__(64) void agg1_kernel(const u8* __restrict__ h1q,
                                                  const float* __restrict__ as1,
                                                  const float* __restrict__ ad1,
                                                  const int* __restrict__ cnt,
                                                  const int* __restrict__ csr,
                                                  const float* __restrict__ bias1,
                                                  u16* __restrict__ x2) {
    const int lane = threadIdx.x;
    const int dst = blockIdx.x;             // wave-uniform (scalar)
    const int c0 = lane * 16;               // 16 channels per lane
    const int h = lane >> 3;                // head (all 16 lane-channels same head)
    const int base = dst * CAP;

    int idx = csr[base + lane];                     // unclamped: || with cnt load
    const int deg = __builtin_amdgcn_readfirstlane(max(1, min(cnt[dst], CAP)));
    const float adv = ad1[dst * NH + h];            // per-head dst term

    f32x2 acc[8];
    #pragma unroll
    for (int k = 0; k < 8; k++) acc[k] = (f32x2){0.f, 0.f};
    float den = 0.f;

    const int nit = (deg + 7) >> 3;                 // groups of 8
    uint4 qa[8], qb[8];
    float pa[8], pb[8];
    A1_FETCH8(0, qa, pa)
    int g = 0;
    for (; g + 2 < nit; g += 2) {                   // ping-pong
        A1_FETCH8((g + 1) * 8, qb, pb)
        A1_PROC8(g * 8, qa, pa)
        A1_FETCH8((g + 2) * 8, qa, pa)
        A1_PROC8((g + 1) * 8, qb, pb)
    }
    if (g + 1 < nit) {
        A1_FETCH8((g + 1) * 8, qb, pb)
        A1_PROC8(g * 8, qa, pa)
        A1_PROC8((g + 1) * 8, qb, pb)
    } else {
        A1_PROC8(g * 8, qa, pa)
    }

    float inv = 1.f / (den + 1e-16f);
    u16 ov[16];
    #pragma unroll
    for (int k = 0; k < 8; k++) {
        float a0 = acc[k][0] * inv + bias1[c0 + 2 * k];
        float a1 = acc[k][1] * inv + bias1[c0 + 2 * k + 1];
        a0 = a0 > 0.f ? a0 : (__expf(a0) - 1.f);   // ELU (abs err ~1e-7, tol 0.03)
        a1 = a1 > 0.f ? a1 : (__expf(a1) - 1.f);
        ov[2 * k] = f2bf(a0);
        ov[2 * k + 1] = f2bf(a1);
    }
    *(uint4*)(x2 + (size_t)dst * D1 + c0) = *(const uint4*)ov;
    *(uint4*)(x2 + (size_t)dst * D1 + c0 + 8) = *(const uint4*)(ov + 8);
}

// ---------- layer-2 softmax-aggregate + log_softmax (1-WAVE BLOCKS) ----------
// ONE 64-thread block per dst; hoisted den / pre-masked pl / scalar-fmaf.
#define A2_FETCH8(E0, Q)                                                      \
    {                                                                         \
        _Pragma("unroll")                                                     \
        for (int u = 0; u < 8; u++) {                                         \
            int s = __builtin_amdgcn_readlane(idx, (E0) + u);                 \
            s = s < 0 ? 0 : (s > NN - 1 ? NN - 1 : s);                        \
            Q[u] = *(const unsigned int*)(h2 + (size_t)s * C2 + lane2);       \
        }                                                                     \
        __builtin_amdgcn_sched_barrier(0);                                    \
    }
#define A2_PROC8(E0, Q)                                                       \
    {                                                                         \
        _Pragma("unroll")                                                     \
        for (int u = 0; u < 8; u++) {                                         \
            float pp = __uint_as_float(__builtin_amdgcn_readlane(             \
                __float_as_uint(pl), (E0) + u));                              \
            float f0 = __uint_as_float((Q)[u] << 16);                         \
            float f1 = __uint_as_float((Q)[u] & 0xFFFF0000u);                 \
            a0 = fmaf(pp, f0, a0);                                            \
            a1 = fmaf(pp, f1, a1);                                            \
        }                                                                     \
    }

__global__ __launch_bounds__(64) void agg2_kernel(const u16* __restrict__ h2,
                                                  const float* __restrict__ as2,
                                                  const float* __restrict__ ad2,
                                                  const int* __restrict__ cnt,
                                                  const int* __restrict__ csr,
                                                  const float* __restrict__ bias2,
                                                  float* __restrict__ out) {
    const int lane = threadIdx.x;
    const int dst = blockIdx.x;                 // wave-uniform (scalar)
    const int base = dst * CAP;
    const int lane2 = lane * 2;

    int idx = csr[base + lane];                 // coalesced; || with cnt
    const int deg = max(1, min(cnt[dst], CAP)); // scalar
    const float adv = ad2[dst];
    int idxc = idx < 0 ? 0 : (idx > NN - 1 ? NN - 1 : idx);
    float ev = as2[idxc] + adv;                 // random 4B within 80 KB (L2)
    ev = ev > 0.f ? ev : 0.2f * ev;
    float pl = (lane < deg) ? __expf(ev) : 0.f; // masked ONCE
    float den = bred_sum(pl);                   // hoisted

    float a0 = 0.f, a1 = 0.f;

    const int nit = (deg + 7) >> 3;
    unsigned int qa[8], qb[8];
    A2_FETCH8(0, qa)
    int g = 0;
    for (; g + 2 < nit; g += 2) {
        A2_FETCH8((g + 1) * 8, qb)
        A2_PROC8(g * 8, qa)
        A2_FETCH8((g + 2) * 8, qa)
        A2_PROC8((g + 1) * 8, qb)
    }
    if (g + 1 < nit) {
        A2_FETCH8((g + 1) * 8, qb)
        A2_PROC8(g * 8, qa)
        A2_PROC8((g + 1) * 8, qb)
    } else {
        A2_PROC8(g * 8, qa)
    }

    float inv = 1.f / (den + 1e-16f);
    float l0 = a0 * inv + bias2[lane2];
    float l1 = a1 * inv + bias2[lane2 + 1];
    // log_softmax over the wave's 128 channels
    float m = bred_max(fmaxf(l0, l1));
    float ex = bred_sum(__expf(l0 - m) + __expf(l1 - m));
    float lse = m + __logf(ex);
    float2 ov = {l0 - lse, l1 - lse};
    *(float2*)(out + (size_t)dst * C2 + lane2) = ov;
}

extern "C" void kernel_launch(void* const* d_in, const int* in_sizes, int n_in,
                              void* d_out, int out_size, void* d_ws, size_t ws_size,
                              hipStream_t stream) {
    const float* x        = (const float*)d_in[0];
    const int*   ei       = (const int*)d_in[1];
    const float* W1       = (const float*)d_in[2];
    const float* att_src1 = (const float*)d_in[3];
    const float* att_dst1 = (const float*)d_in[4];
    const float* bias1    = (const float*)d_in[5];
    const float* W2       = (const float*)d_in[6];
    const float* att_src2 = (const float*)d_in[7];
    const float* att_dst2 = (const float*)d_in[8];
    const float* bias2    = (const float*)d_in[9];
    float* out = (float*)d_out;
    const int E = in_sizes[1] / 2;

    char* ws = (char*)d_ws;
    size_t off = 0;
    auto alloc = [&](size_t b) {
        void* p = ws + off;
        off += (b + 255) & ~(size_t)255;
        return p;
    };
    u8*  h1q  = (u8*)alloc((size_t)NN * D1);
    u16* x2   = (u16*)alloc((size_t)NN * D1 * 2);
    u16* h2   = (u16*)alloc((size_t)NN * C2 * 2);
    u16* xb   = (u16*)alloc((size_t)NN * FIN * 2);
    u16* w1t  = (u16*)alloc((size_t)D1 * FIN * 2);
    u16* w2t  = (u16*)alloc((size_t)C2 * D1 * 2);
    float* as1 = (float*)alloc((size_t)NN * NH * 4);
    float* ad1 = (float*)alloc((size_t)NN * NH * 4);
    float* as2 = (float*)alloc((size_t)NN * 4);
    float* ad2 = (float*)alloc((size_t)NN * 4);
    int* cnt  = (int*)alloc((size_t)NN * 4);
    int* csr  = (int*)alloc((size_t)NN * CAP * 4);

    // zero cnt up front; fused prep then casts x, transposes W1/W2 AND
    // fills the CSR buckets (fill overlaps the BW-heavy cast blocks)
    hipMemsetAsync(cnt, 0, (size_t)NN * 4, stream);
    const int FILL_BLOCKS = (E + NN + 255) / 256;
    prep_kernel<<<5384 + FILL_BLOCKS, 256, 0, stream>>>(x, xb, W1, w1t, W2, w2t,
                                                        ei, E, cnt, csr);

    // layer 1 GEMM: h1q fp8 + fused per-head as1/ad1. XCD-cohort grid:
    // 157 row-tiles -> 20 groups of 8 slots x 8 heads = 1280 blocks
    // (24 holes exit early); heads of one row-tile share an XCD's L2.
    gemm_mfma<128, 32, 2><<<1280, 256, 0, stream>>>(
        xb, w1t, h1q, att_src1, att_dst1, as1, ad1, NH, NN, D1, FIN);
    // 1-wave blocks: one dst per 64-thread block, scheduler backfills
    agg1_kernel<<<NN, 64, 0, stream>>>(h1q, as1, ad1, cnt, csr, bias1, x2);
    // layer 2 GEMM: h2 bf16 + fused as2/ad2 (R7-proven BM=64/BK=32)
    gemm_mfma<64, 32, 1><<<dim3((NN + 63) / 64, 1), 256, 0, stream>>>(
        x2, w2t, h2, att_src2, att_dst2, as2, ad2, 1, NN, C2, D1);
    agg2_kernel<<<NN, 64, 0, stream>>>(h2, as2, ad2, cnt, csr, bias2, out);
}